// Round 9
// baseline (898.277 us; speedup 1.0000x reference)
//
#include <hip/hip_runtime.h>

typedef __attribute__((ext_vector_type(8))) short bf16x8;
typedef __attribute__((ext_vector_type(4))) float f32x4;

#define NBLK 512
#define NTHR 512    // 8 waves; 1 block/CU resident (128 KB LDS)
#define DOUT 128

__device__ __forceinline__ unsigned short bf_rne(float x) {
  unsigned u = __builtin_bit_cast(unsigned, x);
  return (unsigned short)((u + 0x7FFFu + ((u >> 16) & 1u)) >> 16);
}

// fp32 -> bf16 hi (truncate) + bf16 lo (RNE of residual); x ~ hi+lo to ~2^-15 rel
__device__ __forceinline__ void split2(float x, short& hi, short& lo) {
  unsigned u = __builtin_bit_cast(unsigned, x);
  float hf = __builtin_bit_cast(float, u & 0xFFFF0000u);
  hi = (short)(unsigned short)(u >> 16);
  lo = (short)bf_rne(x - hf);
}

// Autonomous-wave design, v3 (pipeline-slack fix).
// R8 showed: (512,2) -> 120V/128 cap, no spill, but HBM 2.3 TB/s — allocator
// at the edge sinks refill loads to their consumers, collapsing prefetch
// depth. v3 halves per-step state (rt=1: acc[8]=32 AGPR, 8-reg slots) and
// uses 4 aligned slots (ks&3) in a non-unrolled pass loop so the scheduler
// keeps a steady-state 4-deep pipeline with ~45 VGPRs of slack.
//  - masked+split weights in LDS once (128 KB); zero main-loop barriers
//  - per wave: 128 rows = 8 passes x 16 rows; 8 k-steps/pass
//  - MFMA swapped (W=A, x=B): lane stores f32x4 of 4 contiguous out cols
__global__ __launch_bounds__(NTHR, 2)
void dagmm(const float* __restrict__ x0, const float* __restrict__ x1,
           const float* __restrict__ w0, const float* __restrict__ w1,
           const float* __restrict__ m0, const float* __restrict__ m1,
           float* __restrict__ out)
{
  __shared__ short wl[65536];   // 128 KB masked+split weights

  const int t   = threadIdx.x;
  const int l   = t & 63;
  const int w   = t >> 6;       // wave 0..7
  const int l16 = l & 15;
  const int lq  = l >> 4;

  // ---------- stage masked, hi/lo-split weights into LDS (once) ----------
  // layout: cix = ct*8+ks; hi bf16x8 at short-idx cix*1024 + lane*8, lo at +512.
  // lane holds W[col=ct*16+(l&15)][k=ks*32+(l>>4)*8+j] == A-frag for 16x16x32.
#pragma unroll
  for (int rep = 0; rep < 8; ++rep) {
    const int chunk = rep * 512 + t;           // 4096 = 64 cix * 64 lanes
    const int cl  = chunk & 63;
    const int cks = (chunk >> 6) & 7;
    const int cct = (chunk >> 9) & 7;
    const int col = cct * 16 + (cl & 15);
    const int k0  = cks * 32 + ((cl >> 4) << 3);   // 0..248, never straddles 128
    const float* wp = (k0 < 128) ? (w0 + col * 128 + k0) : (w1 + col * 128 + (k0 - 128));
    const float* mp = (k0 < 128) ? (m0 + col * 128 + k0) : (m1 + col * 128 + (k0 - 128));
    float4 wa = *(const float4*)wp, wb = *(const float4*)(wp + 4);
    float4 ma = *(const float4*)mp, mb = *(const float4*)(mp + 4);
    float v[8] = {wa.x*ma.x, wa.y*ma.y, wa.z*ma.z, wa.w*ma.w,
                  wb.x*mb.x, wb.y*mb.y, wb.z*mb.z, wb.w*mb.w};
    bf16x8 hv, lv;
#pragma unroll
    for (int j = 0; j < 8; ++j) { short h, lo2; split2(v[j], h, lo2); hv[j] = h; lv[j] = lo2; }
    const int base = (cct * 8 + cks) * 1024 + cl * 8;
    *(bf16x8*)&wl[base]       = hv;
    *(bf16x8*)&wl[base + 512] = lv;
  }
  __syncthreads();   // only barrier in the kernel

  const int gw = blockIdx.x * 8 + w;       // owns rows [gw*128, gw*128+128)
  const size_t rowbase = (size_t)gw * 128;

  // x address for (pass p, k-step ks): lane reads 8 floats at
  // (row = rowbase + p*16 + l16, k = ks*32 + lq*8)  — the 16x16x32 B-frag.
  auto xaddr = [&](int p, int ks) -> const float* {
    const int k = ks * 32 + lq * 8;        // 0..248, never straddles 128
    const float* bp = (k < 128) ? (x0 + k) : (x1 + (k - 128));
    return bp + (rowbase + p * 16 + l16) * 128;
  };

  // depth-4 prefetch slots (8 VGPRs each), statically indexed by ks&3
  float4 pf[4][2];
#pragma unroll
  for (int s = 0; s < 4; ++s) {
    const float* p0 = xaddr(0, s);
    pf[s][0] = *(const float4*)p0;
    pf[s][1] = *(const float4*)(p0 + 4);
  }

  for (int p = 0; p < 8; ++p) {
    f32x4 acc[8];
#pragma unroll
    for (int ct = 0; ct < 8; ++ct) acc[ct] = (f32x4){0.f, 0.f, 0.f, 0.f};

#pragma unroll
    for (int ks = 0; ks < 8; ++ks) {
      const int sl = ks & 3;               // static after unroll; 8%4==0 keeps
      float4 c0 = pf[sl][0], c1 = pf[sl][1];   // slot phase aligned across passes

      // refill slot for step +4
      if (ks < 4) {                        // static: same pass
        const float* np = xaddr(p, ks + 4);
        pf[sl][0] = *(const float4*)np;
        pf[sl][1] = *(const float4*)(np + 4);
      } else if (p < 7) {                  // wave-uniform: next pass
        const float* np = xaddr(p + 1, ks - 4);
        pf[sl][0] = *(const float4*)np;
        pf[sl][1] = *(const float4*)(np + 4);
      }

      float vv[8] = {c0.x, c0.y, c0.z, c0.w, c1.x, c1.y, c1.z, c1.w};
      bf16x8 xh, xl;
#pragma unroll
      for (int j = 0; j < 8; ++j) { short h, lo2; split2(vv[j], h, lo2); xh[j] = h; xl[j] = lo2; }

#pragma unroll
      for (int ct = 0; ct < 8; ++ct) {
        const int bi = (ct * 8 + ks) * 1024 + l * 8;
        bf16x8 wh  = *(const bf16x8*)&wl[bi];
        bf16x8 wlo = *(const bf16x8*)&wl[bi + 512];
        // W ~ wh+wlo, X ~ xh+xl: wh*xh + wh*xl + wlo*xh (drop wlo*xl ~2^-30)
        acc[ct] = __builtin_amdgcn_mfma_f32_16x16x32_bf16(wh,  xh, acc[ct], 0, 0, 0);
        acc[ct] = __builtin_amdgcn_mfma_f32_16x16x32_bf16(wh,  xl, acc[ct], 0, 0, 0);
        acc[ct] = __builtin_amdgcn_mfma_f32_16x16x32_bf16(wlo, xh, acc[ct], 0, 0, 0);
      }
    }

    // D (swapped): col(l16) = x-row, row(lq*4+r) = out col -> f32x4 stores
    const size_t row = rowbase + p * 16 + l16;
#pragma unroll
    for (int ct = 0; ct < 8; ++ct)
      *(f32x4*)&out[row * DOUT + ct * 16 + lq * 4] = acc[ct];
  }
}

extern "C" void kernel_launch(void* const* d_in, const int* in_sizes, int n_in,
                              void* d_out, int out_size, void* d_ws, size_t ws_size,
                              hipStream_t stream) {
  const float* x0 = (const float*)d_in[0];
  const float* x1 = (const float*)d_in[1];
  const float* w0 = (const float*)d_in[2];
  const float* w1 = (const float*)d_in[3];
  const float* m0 = (const float*)d_in[4];
  const float* m1 = (const float*)d_in[5];
  dagmm<<<NBLK, NTHR, 0, stream>>>(x0, x1, w0, w1, m0, m1, (float*)d_out);
}

// Round 10
// 178.179 us; speedup vs baseline: 5.0414x; 5.0414x over previous
//
#include <hip/hip_runtime.h>

typedef __attribute__((ext_vector_type(8))) short bf16x8;
typedef __attribute__((ext_vector_type(4))) float f32x4;
typedef __attribute__((ext_vector_type(2))) unsigned int u32x2;

#define NBLK 512
#define NTHR 512    // 8 waves; 1 block/CU (128 KB LDS)
#define NT   16     // 64-row tiles per block: 512*16*64 = 524288 rows
#define DOUT 128

__device__ __forceinline__ unsigned short bf_rne(float x) {
  unsigned u = __builtin_bit_cast(unsigned, x);
  return (unsigned short)((u + 0x7FFFu + ((u >> 16) & 1u)) >> 16);
}
// fp32 -> bf16 hi (truncate) + bf16 lo (RNE of residual); x ~ hi+lo to ~2^-15 rel
__device__ __forceinline__ void split2(float x, short& hi, short& lo) {
  unsigned u = __builtin_bit_cast(unsigned, x);
  float hf = __builtin_bit_cast(float, u & 0xFFFF0000u);
  hi = (short)(unsigned short)(u >> 16);
  lo = (short)bf_rne(x - hf);
}

// 16B-granule XOR swizzle: spreads both the frag reads (16 rows x 4 k-slots)
// and the split writes (1 row x 32 granules) across all 32 bank-slots at
// <=2-way (free, m136). Verified by enumeration for both access patterns.
__device__ __forceinline__ int fsw(int row) {
  return ((row & 7) << 2) | ((row >> 3) & 1);
}

// R10: R4 structure + counted-wait discipline.
//  - W (masked, hi/lo-split) in VGPRs per wave (16 cols, 32 regs) [R2-proven]
//  - x: 64-row tiles, double-buffered bf16-split LDS (2 x 64 KB)
//  - each wave reg-loads its 8 rows (8 coalesced float4), splits ONCE,
//    ds_writes swizzled; ALL waves read frags + MFMA (swapped: W=A, x=B)
//  - ONE raw barrier per iter: lgkmcnt(0) only — tile t+2's global loads
//    stay in flight across it (no __syncthreads vmcnt(0) drain = R4's bug;
//    no sched_barrier spam = R5's spill trigger)
//  - (512,2): VGPR cap 128 (unified-file law: cap=256/arg); body ~105 regs
__global__ __launch_bounds__(NTHR, 2)
void dagmm(const float* __restrict__ x0, const float* __restrict__ x1,
           const float* __restrict__ w0, const float* __restrict__ w1,
           const float* __restrict__ m0, const float* __restrict__ m1,
           float* __restrict__ out)
{
  __shared__ __align__(16) char L[131072];   // 2 bufs x (32 KB hi + 32 KB lo)

  const int t_   = threadIdx.x;
  const int l    = t_ & 63;
  const int w    = t_ >> 6;     // wave 0..7 -> owns output cols [w*16, w*16+16)
  const int l16  = l & 15;
  const int lq   = l >> 4;

  // ---------- W preamble: masked + split frags in VGPRs (R2-proven) ----------
  // A-frag (16x16x32): lane holds row(=out col) = w*16+l16, k = lq*8 + j
  bf16x8 bhi[8], blo[8];
  {
    const int col = w * 16 + l16;
#pragma unroll
    for (int ks = 0; ks < 8; ++ks) {
      const int k0 = ks * 32 + lq * 8;            // never straddles 128
      const float* wp = (k0 < 128) ? (w0 + col * 128 + k0) : (w1 + col * 128 + (k0 - 128));
      const float* mp = (k0 < 128) ? (m0 + col * 128 + k0) : (m1 + col * 128 + (k0 - 128));
      float4 wa = *(const float4*)wp, wb = *(const float4*)(wp + 4);
      float4 ma = *(const float4*)mp, mb = *(const float4*)(mp + 4);
      float v[8] = {wa.x*ma.x, wa.y*ma.y, wa.z*ma.z, wa.w*ma.w,
                    wb.x*mb.x, wb.y*mb.y, wb.z*mb.z, wb.w*mb.w};
      bf16x8 hv, lv;
#pragma unroll
      for (int j = 0; j < 8; ++j) { short h, lo2; split2(v[j], h, lo2); hv[j] = h; lv[j] = lo2; }
      bhi[ks] = hv; blo[ks] = lv;
    }
  }

  // ---------- staging: lane reads 4 floats (k = l*4..+3) of one row ----------
  const float* xb = (l < 32) ? (x0 + l * 4) : (x1 + (l - 32) * 4);
  const size_t Tbase = (size_t)blockIdx.x * NT * 64;

  float4 pf[8];   // tile rows w*8 .. w*8+7, one float4 per row

#define LOADREG(tt)                                                          \
  {                                                                          \
    _Pragma("unroll")                                                        \
    for (int s = 0; s < 8; ++s)                                              \
      pf[s] = *(const float4*)(xb + (Tbase + (size_t)(tt) * 64 + w * 8 + s) * 128); \
  }

  // split staged regs -> swizzled bf16 hi/lo planes of buffer b
#define SPLITWRITE(b)                                                        \
  {                                                                          \
    _Pragma("unroll")                                                        \
    for (int s = 0; s < 8; ++s) {                                            \
      const int row = w * 8 + s;                                             \
      short h0,h1,h2,h3, e0,e1,e2,e3;                                        \
      split2(pf[s].x, h0, e0); split2(pf[s].y, h1, e1);                      \
      split2(pf[s].z, h2, e2); split2(pf[s].w, h3, e3);                      \
      u32x2 hv, lv;                                                          \
      hv[0] = (unsigned short)h0 | ((unsigned)(unsigned short)h1 << 16);     \
      hv[1] = (unsigned short)h2 | ((unsigned)(unsigned short)h3 << 16);     \
      lv[0] = (unsigned short)e0 | ((unsigned)(unsigned short)e1 << 16);     \
      lv[1] = (unsigned short)e2 | ((unsigned)(unsigned short)e3 << 16);     \
      const int base = (b) * 65536 + row * 512 + (((l >> 1) ^ fsw(row)) << 4) + (l & 1) * 8; \
      *(u32x2*)(L + base)         = hv;                                      \
      *(u32x2*)(L + base + 32768) = lv;                                      \
    }                                                                        \
  }

  // ---------- prologue: tile0 -> buf0; tile1 -> regs ----------
  LOADREG(0);
  SPLITWRITE(0);
  LOADREG(1);
  asm volatile("s_waitcnt lgkmcnt(0)" ::: "memory");
  __builtin_amdgcn_s_barrier();
  asm volatile("" ::: "memory");

  for (int t = 0; t < NT; ++t) {
    // 1) split tile t+1 (staged one iter ago; vmcnt wait ~free) -> other buf
    if (t + 1 < NT) SPLITWRITE((t + 1) & 1);
    // 2) issue tile t+2's loads -> in flight across barrier + next compute
    if (t + 2 < NT) LOADREG(t + 2);

    // 3) compute tile t from buf[t&1]: 4 row-frags x 8 ks x 3 MFMA
    f32x4 acc[4];
#pragma unroll
    for (int rt = 0; rt < 4; ++rt) acc[rt] = (f32x4){0.f, 0.f, 0.f, 0.f};

    const int bb = (t & 1) * 65536;
#pragma unroll
    for (int ks = 0; ks < 8; ++ks) {
#pragma unroll
      for (int rt = 0; rt < 4; ++rt) {
        const int row = rt * 16 + l16;
        const int ba  = bb + row * 512 + (((ks * 4 + lq) ^ fsw(row)) << 4);
        bf16x8 xh = *(const bf16x8*)(L + ba);
        bf16x8 xl = *(const bf16x8*)(L + ba + 32768);
        // W ~ bhi+blo, X ~ xh+xl: keep 3 terms (drop blo*xl ~2^-30)
        acc[rt] = __builtin_amdgcn_mfma_f32_16x16x32_bf16(bhi[ks], xh, acc[rt], 0, 0, 0);
        acc[rt] = __builtin_amdgcn_mfma_f32_16x16x32_bf16(bhi[ks], xl, acc[rt], 0, 0, 0);
        acc[rt] = __builtin_amdgcn_mfma_f32_16x16x32_bf16(blo[ks], xh, acc[rt], 0, 0, 0);
      }
    }

    // D (swapped): lane l16 = x-row, lq*4+r = out col -> coalesced f32x4
#pragma unroll
    for (int rt = 0; rt < 4; ++rt) {
      const size_t row = Tbase + (size_t)t * 64 + rt * 16 + l16;
      *(f32x4*)&out[row * DOUT + w * 16 + lq * 4] = acc[rt];
    }

    // 4) one raw barrier: ds ops drained, global loads stay in flight
    asm volatile("s_waitcnt lgkmcnt(0)" ::: "memory");
    __builtin_amdgcn_s_barrier();
    asm volatile("" ::: "memory");
  }
}

extern "C" void kernel_launch(void* const* d_in, const int* in_sizes, int n_in,
                              void* d_out, int out_size, void* d_ws, size_t ws_size,
                              hipStream_t stream) {
  const float* x0 = (const float*)d_in[0];
  const float* x1 = (const float*)d_in[1];
  const float* w0 = (const float*)d_in[2];
  const float* w1 = (const float*)d_in[3];
  const float* m0 = (const float*)d_in[4];
  const float* m1 = (const float*)d_in[5];
  dagmm<<<NBLK, NTHR, 0, stream>>>(x0, x1, w0, w1, m0, m1, (float*)d_out);
}